// Round 2
// baseline (317.487 us; speedup 1.0000x reference)
//
#include <hip/hip_runtime.h>
#include <cstdint>
#include <cstddef>

#define N_ 4096
#define C_ 256

typedef _Float16 h8 __attribute__((ext_vector_type(8)));
typedef _Float16 h4 __attribute__((ext_vector_type(4)));
typedef float f4 __attribute__((ext_vector_type(4)));

__device__ __forceinline__ void gl2lds16(const void* g, void* l) {
  __builtin_amdgcn_global_load_lds((const __attribute__((address_space(1))) void*)g,
                                   (__attribute__((address_space(3))) void*)l, 16, 0, 0);
}

// ---- branch-free exact top-16 primitives.
// f32 key + i32 idx companion CEs (cmp + cndmask x4 = 10 cyc vs 16 for f64 CE;
// f64 min/max measured ~8 cyc = quarter rate). idx packed into f64 only at
// publish, so pd / k_kmerge semantics unchanged.

// bitonic sort of 8 (key,idx) pairs, ascending by key.
__device__ __forceinline__ void sort8p(float* k, int* x) {
#pragma unroll
  for (int kk = 2; kk <= 8; kk <<= 1)
#pragma unroll
    for (int j = kk >> 1; j > 0; j >>= 1)
#pragma unroll
      for (int i = 0; i < 8; i++) {
        int l = i ^ j;
        if (l > i) {
          bool up = ((i & kk) == 0);
          bool sw = up ? (k[i] > k[l]) : (k[i] < k[l]);
          float a = sw ? k[l] : k[i];
          float b = sw ? k[i] : k[l];
          int ai = sw ? x[l] : x[i];
          int bi = sw ? x[i] : x[l];
          k[i] = a; k[l] = b; x[i] = ai; x[l] = bi;
        }
      }
}

// karr pairs[0..15] ascending; c pairs[0..7] ascending. After: karr = 16
// smallest of karr ∪ c, ascending (verified construction from f64 version).
__device__ __forceinline__ void merge8p(float* kk_, int* ki,
                                        const float* ck, const int* ci) {
#pragma unroll
  for (int i = 0; i < 8; i++) {
    bool take = ck[7 - i] < kk_[8 + i];
    kk_[8 + i] = take ? ck[7 - i] : kk_[8 + i];
    ki[8 + i]  = take ? ci[7 - i] : ki[8 + i];
  }
#pragma unroll
  for (int j = 8; j > 0; j >>= 1)
#pragma unroll
    for (int i = 0; i < 16; i++) {
      int l = i ^ j;
      if (l > i) {
        bool sw = kk_[i] > kk_[l];
        float a = sw ? kk_[l] : kk_[i];
        float b = sw ? kk_[i] : kk_[l];
        int ai = sw ? ki[l] : ki[i];
        int bi = sw ? ki[i] : ki[l];
        kk_[i] = a; kk_[l] = b; ki[i] = ai; ki[l] = bi;
      }
    }
}

// merge two sorted-16 f64 packed lists, keep 16 smallest (for k_kmerge).
__device__ __forceinline__ void merge16d(double* a, const double* b) {
#pragma unroll
  for (int i = 0; i < 16; i++) a[i] = fmin(a[i], b[15 - i]);
#pragma unroll
  for (int j = 8; j > 0; j >>= 1)
#pragma unroll
    for (int i = 0; i < 16; i++) {
      int l = i ^ j;
      if (l > i) {
        double mn = fmin(a[i], a[l]), mx = fmax(a[i], a[l]);
        a[i] = mn; a[l] = mx;
      }
    }
}

// -------------------------------------- sq = sum x^2 ; split x -> f16 hi + lo
__global__ __launch_bounds__(256) void k_prep(const float* __restrict__ x,
                                              float* __restrict__ sq,
                                              _Float16* __restrict__ xh,
                                              _Float16* __restrict__ xl) {
  int wave = threadIdx.x >> 6, lane = threadIdx.x & 63;
  int row = blockIdx.x * 4 + wave;            // 0..16383
  size_t off = (size_t)row * C_ + lane * 4;
  float4 v = *(const float4*)(x + off);
  h4 hi; hi[0] = (_Float16)v.x; hi[1] = (_Float16)v.y;
         hi[2] = (_Float16)v.z; hi[3] = (_Float16)v.w;
  h4 lo; lo[0] = (_Float16)(v.x - (float)hi[0]); lo[1] = (_Float16)(v.y - (float)hi[1]);
         lo[2] = (_Float16)(v.z - (float)hi[2]); lo[3] = (_Float16)(v.w - (float)hi[3]);
  *(h4*)(xh + off) = hi;
  *(h4*)(xl + off) = lo;
  float s = v.x * v.x + v.y * v.y + v.z * v.z + v.w * v.w;
  s += __shfl_xor(s, 32); s += __shfl_xor(s, 16); s += __shfl_xor(s, 8);
  s += __shfl_xor(s, 4);  s += __shfl_xor(s, 2);  s += __shfl_xor(s, 1);
  if (lane == 0) sq[row] = s;
}

// ------------------- split W into f16 hi/lo, transposed to B-frag row layout
__global__ __launch_bounds__(256) void k_wsplit(const float* __restrict__ Wq,
                                                const float* __restrict__ Wk,
                                                const float* __restrict__ Wv,
                                                _Float16* __restrict__ wh,
                                                _Float16* __restrict__ wl) {
  int g = blockIdx.x * 256 + threadIdx.x;     // 0..196607
  int m = g >> 16, e = g & 65535;
  int k = e >> 8, j = e & 255;
  const float* W = (m == 0) ? Wq : ((m == 1) ? Wk : Wv);
  float v = W[k * 256 + j];
  _Float16 hi = (_Float16)v;
  _Float16 lo = (_Float16)(v - (float)hi);
  wh[m * 65536 + j * 256 + k] = hi;
  wl[m * 65536 + j * 256 + k] = lo;
}

// --------------------------- q/k/v projections via split-f16 MFMA (3 passes)
// grid 768: m(3) x rb(128) x cp(2).
__global__ __launch_bounds__(256, 3) void k_proj(const _Float16* __restrict__ xh,
                                                 const _Float16* __restrict__ xl,
                                                 const _Float16* __restrict__ wh,
                                                 const _Float16* __restrict__ wl,
                                                 const float* __restrict__ bqp,
                                                 const float* __restrict__ bkp,
                                                 const float* __restrict__ bvp,
                                                 float* __restrict__ qf,
                                                 float* __restrict__ kf,
                                                 float* __restrict__ vf) {
  int tid = threadIdx.x;
  int bid = blockIdx.x;
  int m   = bid >> 8;
  int rb  = (bid >> 1) & 127;
  int cp  = bid & 1;
  int wave = tid >> 6, lane = tid & 63, quad = lane >> 4, l16 = lane & 15;
  const float* bb = (m == 0) ? bqp : ((m == 1) ? bkp : bvp);
  float* dst      = (m == 0) ? qf  : ((m == 1) ? kf  : vf);
  int row0 = rb * 128 + wave * 32;

  h8 Ah[2][8], Al[2][8];
#pragma unroll
  for (int rt = 0; rt < 2; rt++)
#pragma unroll
    for (int kc = 0; kc < 8; kc++) {
      size_t off = (size_t)(row0 + rt * 16 + l16) * C_ + kc * 32 + quad * 8;
      Ah[rt][kc] = *(const h8*)(xh + off);
      Al[rt][kc] = *(const h8*)(xl + off);
    }
  const _Float16* whm = wh + (size_t)m * 65536;
  const _Float16* wlm = wl + (size_t)m * 65536;

  f4 acc[2][8];
#pragma unroll
  for (int rt = 0; rt < 2; rt++)
#pragma unroll
    for (int ct = 0; ct < 8; ct++) acc[rt][ct] = f4{0.f, 0.f, 0.f, 0.f};
#pragma unroll
  for (int kc = 0; kc < 8; kc++) {
#pragma unroll
    for (int ct = 0; ct < 8; ct++) {
      int col = cp * 128 + ct * 16 + l16;
      h8 bh = *(const h8*)(whm + (size_t)col * 256 + kc * 32 + quad * 8);
      h8 bl = *(const h8*)(wlm + (size_t)col * 256 + kc * 32 + quad * 8);
#pragma unroll
      for (int rt = 0; rt < 2; rt++) {
        acc[rt][ct] = __builtin_amdgcn_mfma_f32_16x16x32_f16(Ah[rt][kc], bh, acc[rt][ct], 0, 0, 0);
        acc[rt][ct] = __builtin_amdgcn_mfma_f32_16x16x32_f16(Ah[rt][kc], bl, acc[rt][ct], 0, 0, 0);
        acc[rt][ct] = __builtin_amdgcn_mfma_f32_16x16x32_f16(Al[rt][kc], bh, acc[rt][ct], 0, 0, 0);
      }
    }
  }
#pragma unroll
  for (int rt = 0; rt < 2; rt++)
#pragma unroll
    for (int ct = 0; ct < 8; ct++) {
      int col = cp * 128 + ct * 16 + l16;
      float bias = bb[col];
#pragma unroll
      for (int i = 0; i < 4; i++) {
        int r = row0 + rt * 16 + quad * 4 + i;
        dst[(size_t)r * C_ + col] = acc[rt][ct][i] + bias;
      }
    }
}

// ---- split-f16 MFMA distance GEMM + branch-free f32-pair bitonic top-16
// block: 128 targets x 1024 srcs (32-chunks), 4 waves, glds staging.
// bid = ((b*32 + tile)*4 + s4); grid 512 x 256.
__global__ __launch_bounds__(256, 2) void k_knn(const _Float16* __restrict__ xh,
                                                const _Float16* __restrict__ xl,
                                                const float* __restrict__ sq,
                                                double* __restrict__ pd) {
  __shared__ __align__(16) _Float16 Bh[16 * 528]; // 16 segs x (2 rows x 256 + pad)
  __shared__ __align__(16) _Float16 Bl[16 * 528];
  __shared__ __align__(16) float sc[128 * 36];    // row-major d2, stride 36
  __shared__ float sqS[32];

  int tid = threadIdx.x;
  int wave = tid >> 6, lane = tid & 63, quad = lane >> 4, l16 = lane & 15;
  int bid = blockIdx.x;
  int s4 = bid & 3, tile = (bid >> 2) & 31, b = bid >> 7;
  int bN = b * N_, n0 = tile * 128, src0g = s4 * 1024;

  // A-frags: wave's 32 target rows, full K, hi+lo, resident (live in AGPRs)
  h8 Ah[2][8], Al[2][8];
  int tb = bN + n0 + wave * 32;
#pragma unroll
  for (int rt = 0; rt < 2; rt++)
#pragma unroll
    for (int kc = 0; kc < 8; kc++) {
      size_t off = (size_t)(tb + rt * 16 + l16) * C_ + kc * 32 + quad * 8;
      Ah[rt][kc] = *(const h8*)(xh + off);
      Al[rt][kc] = *(const h8*)(xl + off);
    }
  float sqT[2][4];
#pragma unroll
  for (int rt = 0; rt < 2; rt++)
#pragma unroll
    for (int i = 0; i < 4; i++)
      sqT[rt][i] = sq[tb + rt * 16 + quad * 4 + i];

  float karr_k[16]; int karr_i[16];
#pragma unroll
  for (int p = 0; p < 16; p++) { karr_k[p] = 3.0e38f; karr_i[p] = 0; }
  int rowo = tid & 127, half = tid >> 7;

  // prologue: stage chunk 0. seg = 2 src rows = 1KB; lane i -> bytes [16i,16i+16)
  {
    const _Float16* gh = xh + (size_t)(bN + src0g) * C_ + lane * 8;
    const _Float16* gl = xl + (size_t)(bN + src0g) * C_ + lane * 8;
#pragma unroll
    for (int k = 0; k < 4; k++) {
      int seg = wave * 4 + k;
      gl2lds16(gh + seg * 512, &Bh[seg * 528]);
      gl2lds16(gl + seg * 512, &Bl[seg * 528]);
    }
    if (tid < 32) sqS[tid] = sq[bN + src0g + tid];
  }

  int hb0 = ((l16 >> 1) * 528) + ((l16 & 1) * 256) + quad * 8;          // ct=0 row
  int hb1 = (((16 + l16) >> 1) * 528) + ((l16 & 1) * 256) + quad * 8;   // ct=1 row

#pragma unroll 1
  for (int ch = 0; ch < 32; ch++) {
    int src0 = src0g + ch * 32;
    __syncthreads();                       // staged B(ch) + sqS(ch) visible

    f4 acc[2][2];
#pragma unroll
    for (int rt = 0; rt < 2; rt++)
#pragma unroll
      for (int ct = 0; ct < 2; ct++) acc[rt][ct] = f4{0.f, 0.f, 0.f, 0.f};
#pragma unroll
    for (int kc = 0; kc < 8; kc++) {
      h8 bh0 = *(const h8*)(&Bh[hb0 + kc * 32]);
      h8 bh1 = *(const h8*)(&Bh[hb1 + kc * 32]);
      h8 bl0 = *(const h8*)(&Bl[hb0 + kc * 32]);
      h8 bl1 = *(const h8*)(&Bl[hb1 + kc * 32]);
      // round-robin the 4 independent chains so dependent MFMAs are spaced 4
      acc[0][0] = __builtin_amdgcn_mfma_f32_16x16x32_f16(Ah[0][kc], bh0, acc[0][0], 0, 0, 0);
      acc[0][1] = __builtin_amdgcn_mfma_f32_16x16x32_f16(Ah[0][kc], bh1, acc[0][1], 0, 0, 0);
      acc[1][0] = __builtin_amdgcn_mfma_f32_16x16x32_f16(Ah[1][kc], bh0, acc[1][0], 0, 0, 0);
      acc[1][1] = __builtin_amdgcn_mfma_f32_16x16x32_f16(Ah[1][kc], bh1, acc[1][1], 0, 0, 0);
      acc[0][0] = __builtin_amdgcn_mfma_f32_16x16x32_f16(Ah[0][kc], bl0, acc[0][0], 0, 0, 0);
      acc[0][1] = __builtin_amdgcn_mfma_f32_16x16x32_f16(Ah[0][kc], bl1, acc[0][1], 0, 0, 0);
      acc[1][0] = __builtin_amdgcn_mfma_f32_16x16x32_f16(Ah[1][kc], bl0, acc[1][0], 0, 0, 0);
      acc[1][1] = __builtin_amdgcn_mfma_f32_16x16x32_f16(Ah[1][kc], bl1, acc[1][1], 0, 0, 0);
      acc[0][0] = __builtin_amdgcn_mfma_f32_16x16x32_f16(Al[0][kc], bh0, acc[0][0], 0, 0, 0);
      acc[0][1] = __builtin_amdgcn_mfma_f32_16x16x32_f16(Al[0][kc], bh1, acc[0][1], 0, 0, 0);
      acc[1][0] = __builtin_amdgcn_mfma_f32_16x16x32_f16(Al[1][kc], bh0, acc[1][0], 0, 0, 0);
      acc[1][1] = __builtin_amdgcn_mfma_f32_16x16x32_f16(Al[1][kc], bh1, acc[1][1], 0, 0, 0);
    }
    // d2 -> sc row-major (stride 36; 2-way banks max), self-masked
    float sqSr[2] = {sqS[l16], sqS[16 + l16]};
#pragma unroll
    for (int rt = 0; rt < 2; rt++)
#pragma unroll
      for (int ct = 0; ct < 2; ct++) {
        int c = ct * 16 + l16;
#pragma unroll
        for (int i = 0; i < 4; i++) {
          int r = wave * 32 + rt * 16 + quad * 4 + i;
          float d2 = sqT[rt][i] + sqSr[ct] - 2.0f * acc[rt][ct][i];
          if (n0 + r == src0 + c) d2 = 1e38f;
          sc[r * 36 + c] = d2;
        }
      }
    __syncthreads();                       // sc ready; all B(ch) reads done

    if (ch < 31) {                         // async-stage chunk ch+1
      int srcn = src0 + 32;
      const _Float16* gh = xh + (size_t)(bN + srcn) * C_ + lane * 8;
      const _Float16* gl = xl + (size_t)(bN + srcn) * C_ + lane * 8;
#pragma unroll
      for (int k = 0; k < 4; k++) {
        int seg = wave * 4 + k;
        gl2lds16(gh + seg * 512, &Bh[seg * 528]);
        gl2lds16(gl + seg * 512, &Bl[seg * 528]);
      }
      if (tid < 32) sqS[tid] = sq[bN + srcn + tid];
    }

    // merge: 16 candidates (my half-row), two batches of 8 f32-pairs:
    // bitonic sort8 -> min-merge + cleanup. Branch-free, f32-rate CEs.
#pragma unroll
    for (int bt = 0; bt < 2; bt++) {
      float ck[8]; int ci[8];
#pragma unroll
      for (int k4 = 0; k4 < 2; k4++)
        *(float4*)&ck[k4 * 4] = *(const float4*)(&sc[rowo * 36 + half * 16 + bt * 8 + k4 * 4]);
#pragma unroll
      for (int j = 0; j < 8; j++) ci[j] = src0 + half * 16 + bt * 8 + j;
      sort8p(ck, ci);
      merge8p(karr_k, karr_i, ck, ci);
    }
  }

  // combine half-streams: thread t>=128 publishes pairs, t<128 pair-merges,
  // then packs (f64)key | idx and stores pd (same format as before).
  __syncthreads();
  float* scF = sc;
  int*   scI = (int*)sc;
  if (tid >= 128) {
#pragma unroll
    for (int p = 0; p < 16; p++) {
      scF[(tid - 128) * 34 + p]      = karr_k[p];
      scI[(tid - 128) * 34 + 16 + p] = karr_i[p];
    }
  }
  __syncthreads();
  if (tid < 128) {
#pragma unroll
    for (int i = 0; i < 16; i++) {
      float pk = scF[tid * 34 + (15 - i)];
      int   pi = scI[tid * 34 + 16 + (15 - i)];
      bool take = pk < karr_k[i];
      karr_k[i] = take ? pk : karr_k[i];
      karr_i[i] = take ? pi : karr_i[i];
    }
#pragma unroll
    for (int j = 8; j > 0; j >>= 1)
#pragma unroll
      for (int i = 0; i < 16; i++) {
        int l = i ^ j;
        if (l > i) {
          bool sw = karr_k[i] > karr_k[l];
          float a = sw ? karr_k[l] : karr_k[i];
          float bb2 = sw ? karr_k[i] : karr_k[l];
          int ai = sw ? karr_i[l] : karr_i[i];
          int bi = sw ? karr_i[i] : karr_i[l];
          karr_k[i] = a; karr_k[l] = bb2; karr_i[i] = ai; karr_i[l] = bi;
        }
      }
#pragma unroll
    for (int p = 0; p < 16; p++) {
      long long pk = __double_as_longlong((double)karr_k[p]) |
                     (long long)(unsigned)karr_i[p];
      pd[((size_t)bid * 128 + tid) * 16 + p] = __longlong_as_double(pk);
    }
  }
}

// --------------------- merge 4 partial sorted packed lists -> top-16 indices
// branch-free register tree merge (no runtime-indexed arrays -> no scratch);
// grid 256 x 64 so all CUs get work.
__global__ __launch_bounds__(64) void k_kmerge(const double* __restrict__ pd,
                                               int* __restrict__ idxo) {
  int g = blockIdx.x * 64 + threadIdx.x;       // 0..16383
  int b = g >> 12, n = g & 4095;
  int tile = n >> 7, r = n & 127;
  size_t base = (size_t)(((b * 32 + tile) * 4) * 128 + r) * 16;

  double acc[16], other[16];
#pragma unroll
  for (int p = 0; p < 16; p++) acc[p] = pd[base + p];
#pragma unroll
  for (int s = 1; s < 4; s++) {
    size_t bs = base + (size_t)s * 128 * 16;
#pragma unroll
    for (int p = 0; p < 16; p++) other[p] = pd[bs + p];
    merge16d(acc, other);
  }
#pragma unroll
  for (int k = 0; k < 16; k++)
    idxo[(size_t)g * 16 + k] = (int)(__double_as_longlong(acc[k]) & 0xFFF);
}

// -------------------------------------------- gather + attention (wave/node)
__global__ __launch_bounds__(256) void k_attn(const float* __restrict__ qf,
                                              const float* __restrict__ kf,
                                              const float* __restrict__ vf,
                                              const int* __restrict__ idxv,
                                              float* __restrict__ out) {
  int wave = threadIdx.x >> 6, lane = threadIdx.x & 63;
  int g = blockIdx.x * 4 + wave;               // node 0..16383
  int bN = (g >> 12) << 12;
  float4 q4 = *(const float4*)(qf + (size_t)g * C_ + lane * 4);
  int my = idxv[(size_t)g * 16 + (lane & 15)];
  const float scale = 0.17677669529663687f;    // 1/sqrt(32)

  float s[16];
  float4 vv[16];
#pragma unroll
  for (int j = 0; j < 16; j++) {
    int nb = __shfl(my, j);
    size_t base = (size_t)(bN + nb) * C_ + lane * 4;
    float4 k4 = *(const float4*)(kf + base);
    vv[j] = *(const float4*)(vf + base);
    float p = k4.x * q4.x + k4.y * q4.y + k4.z * q4.z + k4.w * q4.w;
    p += __shfl_xor(p, 1); p += __shfl_xor(p, 2); p += __shfl_xor(p, 4);
    s[j] = p * scale;
  }
  float mx = s[0];
#pragma unroll
  for (int j = 1; j < 16; j++) mx = fmaxf(mx, s[j]);
  float den = 0.f;
#pragma unroll
  for (int j = 0; j < 16; j++) { s[j] = __expf(s[j] - mx); den += s[j]; }
  float inv = 1.0f / den;
  float4 o; o.x = 0.f; o.y = 0.f; o.z = 0.f; o.w = 0.f;
#pragma unroll
  for (int j = 0; j < 16; j++) {
    float w = s[j] * inv;
    o.x = fmaf(w, vv[j].x, o.x); o.y = fmaf(w, vv[j].y, o.y);
    o.z = fmaf(w, vv[j].z, o.z); o.w = fmaf(w, vv[j].w, o.w);
  }
  *(float4*)(out + (size_t)g * C_ + lane * 4) = o;
}

extern "C" void kernel_launch(void* const* d_in, const int* in_sizes, int n_in,
                              void* d_out, int out_size, void* d_ws, size_t ws_size,
                              hipStream_t stream) {
  const float* x  = (const float*)d_in[0];
  const float* Wq = (const float*)d_in[1];
  const float* bq = (const float*)d_in[2];
  const float* Wk = (const float*)d_in[3];
  const float* bk = (const float*)d_in[4];
  const float* Wv = (const float*)d_in[5];
  const float* bv = (const float*)d_in[6];
  float* out = (float*)d_out;

  char* ws = (char*)d_ws;
  float*     sqp  = (float*)(ws + 0);                //  64 KB
  _Float16*  xh   = (_Float16*)(ws + 65536);         //   8 MB
  _Float16*  xl   = (_Float16*)(ws + 8454144);       //   8 MB
  float*     qf   = (float*)(ws + 16842752);         //  16 MB
  float*     kf   = (float*)(ws + 33619968);         //  16 MB
  float*     vf   = (float*)(ws + 50397184);         //  16 MB
  double*    pd   = (double*)(ws + 67174400);        //   8 MB
  int*       idxb = (int*)  (ws + 75563008);         //   1 MB
  _Float16*  whf  = (_Float16*)(ws + 76611584);      // 384 KB
  _Float16*  wlf  = (_Float16*)(ws + 77004800);      // 384 KB (total ~74 MB)

  k_prep  <<<4096, 256, 0, stream>>>(x, sqp, xh, xl);
  k_wsplit<<<768,  256, 0, stream>>>(Wq, Wk, Wv, whf, wlf);
  k_proj  <<<768,  256, 0, stream>>>(xh, xl, whf, wlf, bq, bk, bv, qf, kf, vf);
  k_knn   <<<512,  256, 0, stream>>>(xh, xl, sqp, pd);
  k_kmerge<<<256,  64,  0, stream>>>(pd, idxb);
  k_attn  <<<4096, 256, 0, stream>>>(qf, kf, vf, idxb, out);
}

// Round 5
// 291.848 us; speedup vs baseline: 1.0878x; 1.0878x over previous
//
#include <hip/hip_runtime.h>
#include <cstdint>
#include <cstddef>

#define N_ 4096
#define C_ 256

typedef _Float16 h8 __attribute__((ext_vector_type(8)));
typedef _Float16 h4 __attribute__((ext_vector_type(4)));
typedef float f4 __attribute__((ext_vector_type(4)));

__device__ __forceinline__ void gl2lds16(const void* g, void* l) {
  __builtin_amdgcn_global_load_lds((const __attribute__((address_space(1))) void*)g,
                                   (__attribute__((address_space(3))) void*)l, 16, 0, 0);
}

// ---- branch-free exact top-16 primitives (f64 packed keys: key = (double)d2
// with the 12-bit source index OR'd into the low mantissa bits). f64 min/max
// are full-rate on CDNA4 (round-2 lesson: f32 pair-CE = cmp+4 cndmask is
// 2.5x the VALU issue of fmin/fmax f64 -> keep f64).
__device__ __forceinline__ void ce_asc(double& a, double& b) {
  double mn = fmin(a, b), mx = fmax(a, b);
  a = mn; b = mx;
}

// bitonic sort of 8 keys, ascending. 24 CEs, layers of 4 independent CEs.
__device__ __forceinline__ void sort8_asc(double* c) {
#pragma unroll
  for (int k = 2; k <= 8; k <<= 1)
#pragma unroll
    for (int j = k >> 1; j > 0; j >>= 1)
#pragma unroll
      for (int i = 0; i < 8; i++) {
        int l = i ^ j;
        if (l > i) {
          bool up = ((i & k) == 0);
          double a = c[i], b = c[l];
          double mn = fmin(a, b), mx = fmax(a, b);
          c[i] = up ? mn : mx;
          c[l] = up ? mx : mn;
        }
      }
}

// karr[0..15] ascending; c[0..7] ascending. After: karr = 16 smallest of
// karr ∪ c, ascending. Exact (elementwise-min of asc/desc is bitonic).
__device__ __forceinline__ void merge8_top16(double* karr, const double* c) {
#pragma unroll
  for (int i = 0; i < 8; i++)
    karr[8 + i] = fmin(karr[8 + i], c[7 - i]);
#pragma unroll
  for (int j = 8; j > 0; j >>= 1)
#pragma unroll
    for (int i = 0; i < 16; i++) {
      int l = i ^ j;
      if (l > i) ce_asc(karr[i], karr[l]);
    }
}

// merge two sorted-16 f64 packed lists, keep 16 smallest (for k_kmerge).
__device__ __forceinline__ void merge16d(double* a, const double* b) {
#pragma unroll
  for (int i = 0; i < 16; i++) a[i] = fmin(a[i], b[15 - i]);
#pragma unroll
  for (int j = 8; j > 0; j >>= 1)
#pragma unroll
    for (int i = 0; i < 16; i++) {
      int l = i ^ j;
      if (l > i) {
        double mn = fmin(a[i], a[l]), mx = fmax(a[i], a[l]);
        a[i] = mn; a[l] = mx;
      }
    }
}

// -------------------------------------- sq = sum x^2 ; split x -> f16 hi + lo
__global__ __launch_bounds__(256) void k_prep(const float* __restrict__ x,
                                              float* __restrict__ sq,
                                              _Float16* __restrict__ xh,
                                              _Float16* __restrict__ xl) {
  int wave = threadIdx.x >> 6, lane = threadIdx.x & 63;
  int row = blockIdx.x * 4 + wave;            // 0..16383
  size_t off = (size_t)row * C_ + lane * 4;
  float4 v = *(const float4*)(x + off);
  h4 hi; hi[0] = (_Float16)v.x; hi[1] = (_Float16)v.y;
         hi[2] = (_Float16)v.z; hi[3] = (_Float16)v.w;
  h4 lo; lo[0] = (_Float16)(v.x - (float)hi[0]); lo[1] = (_Float16)(v.y - (float)hi[1]);
         lo[2] = (_Float16)(v.z - (float)hi[2]); lo[3] = (_Float16)(v.w - (float)hi[3]);
  *(h4*)(xh + off) = hi;
  *(h4*)(xl + off) = lo;
  float s = v.x * v.x + v.y * v.y + v.z * v.z + v.w * v.w;
  s += __shfl_xor(s, 32); s += __shfl_xor(s, 16); s += __shfl_xor(s, 8);
  s += __shfl_xor(s, 4);  s += __shfl_xor(s, 2);  s += __shfl_xor(s, 1);
  if (lane == 0) sq[row] = s;
}

// ------------------- split W into f16 hi/lo, transposed to B-frag row layout
__global__ __launch_bounds__(256) void k_wsplit(const float* __restrict__ Wq,
                                                const float* __restrict__ Wk,
                                                const float* __restrict__ Wv,
                                                _Float16* __restrict__ wh,
                                                _Float16* __restrict__ wl) {
  int g = blockIdx.x * 256 + threadIdx.x;     // 0..196607
  int m = g >> 16, e = g & 65535;
  int k = e >> 8, j = e & 255;
  const float* W = (m == 0) ? Wq : ((m == 1) ? Wk : Wv);
  float v = W[k * 256 + j];
  _Float16 hi = (_Float16)v;
  _Float16 lo = (_Float16)(v - (float)hi);
  wh[m * 65536 + j * 256 + k] = hi;
  wl[m * 65536 + j * 256 + k] = lo;
}

// --------------------------- q/k/v projections via split-f16 MFMA (3 passes)
// grid 768: m(3) x rb(128) x cp(2).
__global__ __launch_bounds__(256, 3) void k_proj(const _Float16* __restrict__ xh,
                                                 const _Float16* __restrict__ xl,
                                                 const _Float16* __restrict__ wh,
                                                 const _Float16* __restrict__ wl,
                                                 const float* __restrict__ bqp,
                                                 const float* __restrict__ bkp,
                                                 const float* __restrict__ bvp,
                                                 float* __restrict__ qf,
                                                 float* __restrict__ kf,
                                                 float* __restrict__ vf) {
  int tid = threadIdx.x;
  int bid = blockIdx.x;
  int m   = bid >> 8;
  int rb  = (bid >> 1) & 127;
  int cp  = bid & 1;
  int wave = tid >> 6, lane = tid & 63, quad = lane >> 4, l16 = lane & 15;
  const float* bb = (m == 0) ? bqp : ((m == 1) ? bkp : bvp);
  float* dst      = (m == 0) ? qf  : ((m == 1) ? kf  : vf);
  int row0 = rb * 128 + wave * 32;

  h8 Ah[2][8], Al[2][8];
#pragma unroll
  for (int rt = 0; rt < 2; rt++)
#pragma unroll
    for (int kc = 0; kc < 8; kc++) {
      size_t off = (size_t)(row0 + rt * 16 + l16) * C_ + kc * 32 + quad * 8;
      Ah[rt][kc] = *(const h8*)(xh + off);
      Al[rt][kc] = *(const h8*)(xl + off);
    }
  const _Float16* whm = wh + (size_t)m * 65536;
  const _Float16* wlm = wl + (size_t)m * 65536;

  f4 acc[2][8];
#pragma unroll
  for (int rt = 0; rt < 2; rt++)
#pragma unroll
    for (int ct = 0; ct < 8; ct++) acc[rt][ct] = f4{0.f, 0.f, 0.f, 0.f};
#pragma unroll
  for (int kc = 0; kc < 8; kc++) {
#pragma unroll
    for (int ct = 0; ct < 8; ct++) {
      int col = cp * 128 + ct * 16 + l16;
      h8 bh = *(const h8*)(whm + (size_t)col * 256 + kc * 32 + quad * 8);
      h8 bl = *(const h8*)(wlm + (size_t)col * 256 + kc * 32 + quad * 8);
#pragma unroll
      for (int rt = 0; rt < 2; rt++) {
        acc[rt][ct] = __builtin_amdgcn_mfma_f32_16x16x32_f16(Ah[rt][kc], bh, acc[rt][ct], 0, 0, 0);
        acc[rt][ct] = __builtin_amdgcn_mfma_f32_16x16x32_f16(Ah[rt][kc], bl, acc[rt][ct], 0, 0, 0);
        acc[rt][ct] = __builtin_amdgcn_mfma_f32_16x16x32_f16(Al[rt][kc], bh, acc[rt][ct], 0, 0, 0);
      }
    }
  }
#pragma unroll
  for (int rt = 0; rt < 2; rt++)
#pragma unroll
    for (int ct = 0; ct < 8; ct++) {
      int col = cp * 128 + ct * 16 + l16;
      float bias = bb[col];
#pragma unroll
      for (int i = 0; i < 4; i++) {
        int r = row0 + rt * 16 + quad * 4 + i;
        dst[(size_t)r * C_ + col] = acc[rt][ct][i] + bias;
      }
    }
}

// ---- split-f16 MFMA distance GEMM + f64 bitonic top-16, single-barrier
// pipelined: LDS double-buffered B (stage ch+1 while computing ch -> the
// vmcnt drain at the next barrier is a full chunk deep = ~free), wave-private
// d2 exchange (no second block barrier). 128 targets x 1024 srcs per block,
// 4 waves. bid = ((b*32 + tile)*4 + s4); grid 512 x 256.
__global__ __launch_bounds__(256, 2) void k_knn(const _Float16* __restrict__ xh,
                                                const _Float16* __restrict__ xl,
                                                const float* __restrict__ sq,
                                                double* __restrict__ pd) {
  __shared__ __align__(16) _Float16 Bh[2][16 * 528]; // dbuf: 16 segs x (2x256 + 8 pad)
  __shared__ __align__(16) _Float16 Bl[2][16 * 528];
  __shared__ __align__(16) float sc[4][16 * 36];     // per-wave exchange, stride 36

  int tid = threadIdx.x;
  int wave = tid >> 6, lane = tid & 63, quad = lane >> 4, l16 = lane & 15;
  int bid = blockIdx.x;
  int s4 = bid & 3, tile = (bid >> 2) & 31, b = bid >> 7;
  int bN = b * N_, n0 = tile * 128, src0g = s4 * 1024;

  // A-frags: wave's 32 target rows, full K, hi+lo, resident (live in AGPRs)
  h8 Ah[2][8], Al[2][8];
  int tb = bN + n0 + wave * 32;
#pragma unroll
  for (int rt = 0; rt < 2; rt++)
#pragma unroll
    for (int kc = 0; kc < 8; kc++) {
      size_t off = (size_t)(tb + rt * 16 + l16) * C_ + kc * 32 + quad * 8;
      Ah[rt][kc] = *(const h8*)(xh + off);
      Al[rt][kc] = *(const h8*)(xl + off);
    }
  float sqT[2][4];
#pragma unroll
  for (int rt = 0; rt < 2; rt++)
#pragma unroll
    for (int i = 0; i < 4; i++)
      sqT[rt][i] = sq[tb + rt * 16 + quad * 4 + i];

  double karr[16];
#pragma unroll
  for (int p = 0; p < 16; p++) karr[p] = 1e300;
  int rloc = lane & 31;            // owned row within this wave's 32-row group
  int half = lane >> 5;            // candidate half (0: cols 0-15, 1: 16-31)
  int rown = wave * 32 + rloc;     // owned row within block (0..127)
  int rt_owner = rloc >> 4;        // which rt sub-round produces my row
  int rl = rloc & 15;              // row within the 16-row exchange tile

  // prologue: stage chunk 0 -> buf 0. seg = 2 src rows = 1KB.
  {
    const _Float16* gh = xh + (size_t)(bN + src0g) * C_ + lane * 8;
    const _Float16* gl = xl + (size_t)(bN + src0g) * C_ + lane * 8;
#pragma unroll
    for (int k = 0; k < 4; k++) {
      int seg = wave * 4 + k;
      gl2lds16(gh + seg * 512, &Bh[0][seg * 528]);
      gl2lds16(gl + seg * 512, &Bl[0][seg * 528]);
    }
  }

  int hb0 = ((l16 >> 1) * 528) + ((l16 & 1) * 256) + quad * 8;          // ct=0 row
  int hb1 = (((16 + l16) >> 1) * 528) + ((l16 & 1) * 256) + quad * 8;   // ct=1 row

#pragma unroll 1
  for (int ch = 0; ch < 32; ch++) {
    int src0 = src0g + ch * 32;
    int buf = ch & 1;
    __syncthreads();   // buf's glds (issued one full chunk ago) drained here;
                       // everyone done reading buf^1 -> safe to overwrite it

    if (ch < 31) {     // issue staging of chunk ch+1 -> buf^1 (waited next iter)
      int srcn = src0 + 32;
      const _Float16* gh = xh + (size_t)(bN + srcn) * C_ + lane * 8;
      const _Float16* gl = xl + (size_t)(bN + srcn) * C_ + lane * 8;
#pragma unroll
      for (int k = 0; k < 4; k++) {
        int seg = wave * 4 + k;
        gl2lds16(gh + seg * 512, &Bh[buf ^ 1][seg * 528]);
        gl2lds16(gl + seg * 512, &Bl[buf ^ 1][seg * 528]);
      }
    }
    // source sq for this chunk's two column groups (L1/L2-resident)
    float sqc0 = sq[bN + src0 + l16];
    float sqc1 = sq[bN + src0 + 16 + l16];

    f4 acc[2][2];
#pragma unroll
    for (int rt = 0; rt < 2; rt++)
#pragma unroll
      for (int ct = 0; ct < 2; ct++) acc[rt][ct] = f4{0.f, 0.f, 0.f, 0.f};
#pragma unroll
    for (int kc = 0; kc < 8; kc++) {
      h8 bh0 = *(const h8*)(&Bh[buf][hb0 + kc * 32]);
      h8 bh1 = *(const h8*)(&Bh[buf][hb1 + kc * 32]);
      h8 bl0 = *(const h8*)(&Bl[buf][hb0 + kc * 32]);
      h8 bl1 = *(const h8*)(&Bl[buf][hb1 + kc * 32]);
#pragma unroll
      for (int rt = 0; rt < 2; rt++) {
        acc[rt][0] = __builtin_amdgcn_mfma_f32_16x16x32_f16(Ah[rt][kc], bh0, acc[rt][0], 0, 0, 0);
        acc[rt][0] = __builtin_amdgcn_mfma_f32_16x16x32_f16(Ah[rt][kc], bl0, acc[rt][0], 0, 0, 0);
        acc[rt][0] = __builtin_amdgcn_mfma_f32_16x16x32_f16(Al[rt][kc], bh0, acc[rt][0], 0, 0, 0);
        acc[rt][1] = __builtin_amdgcn_mfma_f32_16x16x32_f16(Ah[rt][kc], bh1, acc[rt][1], 0, 0, 0);
        acc[rt][1] = __builtin_amdgcn_mfma_f32_16x16x32_f16(Ah[rt][kc], bl1, acc[rt][1], 0, 0, 0);
        acc[rt][1] = __builtin_amdgcn_mfma_f32_16x16x32_f16(Al[rt][kc], bh1, acc[rt][1], 0, 0, 0);
      }
    }

    // d2 -> per-wave sc exchange, two rt sub-rounds (within-wave ordering only)
    float dv[16];
#pragma unroll
    for (int rt = 0; rt < 2; rt++) {
#pragma unroll
      for (int ct = 0; ct < 2; ct++) {
        int c = ct * 16 + l16;
        float sqSr = ct ? sqc1 : sqc0;
#pragma unroll
        for (int i = 0; i < 4; i++) {
          int r = wave * 32 + rt * 16 + quad * 4 + i;
          float d2 = sqT[rt][i] + sqSr - 2.0f * acc[rt][ct][i];
          if (n0 + r == src0 + c) d2 = 1e38f;
          sc[wave][(quad * 4 + i) * 36 + c] = d2;
        }
      }
      // owners of this rt group read their 16 candidates (b128 x4)
      if (rt_owner == rt) {
#pragma unroll
        for (int j = 0; j < 4; j++)
          *(float4*)&dv[j * 4] = *(const float4*)(&sc[wave][rl * 36 + half * 16 + j * 4]);
      }
      asm volatile("" ::: "memory");   // keep rt=1 writes after rt=0 reads
    }

    // merge: 16 candidates, two batches of 8: pack f64 -> sort8 -> merge.
#pragma unroll
    for (int bt = 0; bt < 2; bt++) {
      double c8[8];
#pragma unroll
      for (int j = 0; j < 8; j++) {
        double key = (double)dv[bt * 8 + j];
        c8[j] = __longlong_as_double(__double_as_longlong(key) |
                                     (unsigned)(src0 + half * 16 + bt * 8 + j));
      }
      sort8_asc(c8);
      merge8_top16(karr, c8);
    }
  }

  // combine the two half-streams of each row (partner lanes L and L+32),
  // through the now-dead Bh region. One barrier pair, once per kernel.
  __syncthreads();
  double* scd = (double*)&Bh[0][0];    // 128 rows x 17 doubles = 17408 B
  if (half) {
#pragma unroll
    for (int p = 0; p < 16; p++) scd[rown * 17 + p] = karr[p];
  }
  __syncthreads();
  if (!half) {
#pragma unroll
    for (int i = 0; i < 16; i++)
      karr[i] = fmin(karr[i], scd[rown * 17 + (15 - i)]);
#pragma unroll
    for (int j = 8; j > 0; j >>= 1)
#pragma unroll
      for (int i = 0; i < 16; i++) {
        int l = i ^ j;
        if (l > i) ce_asc(karr[i], karr[l]);
      }
#pragma unroll
    for (int p = 0; p < 16; p++)
      pd[((size_t)bid * 128 + rown) * 16 + p] = karr[p];
  }
}

// --------------------- merge 4 partial sorted packed lists -> top-16 indices
// branch-free register tree merge; grid 256 x 64 so all CUs get work.
__global__ __launch_bounds__(64) void k_kmerge(const double* __restrict__ pd,
                                               int* __restrict__ idxo) {
  int g = blockIdx.x * 64 + threadIdx.x;       // 0..16383
  int b = g >> 12, n = g & 4095;
  int tile = n >> 7, r = n & 127;
  size_t base = (size_t)(((b * 32 + tile) * 4) * 128 + r) * 16;

  double acc[16], other[16];
#pragma unroll
  for (int p = 0; p < 16; p++) acc[p] = pd[base + p];
#pragma unroll
  for (int s = 1; s < 4; s++) {
    size_t bs = base + (size_t)s * 128 * 16;
#pragma unroll
    for (int p = 0; p < 16; p++) other[p] = pd[bs + p];
    merge16d(acc, other);
  }
#pragma unroll
  for (int k = 0; k < 16; k++)
    idxo[(size_t)g * 16 + k] = (int)(__double_as_longlong(acc[k]) & 0xFFF);
}

// -------------------------------------------- gather + attention (wave/node)
__global__ __launch_bounds__(256) void k_attn(const float* __restrict__ qf,
                                              const float* __restrict__ kf,
                                              const float* __restrict__ vf,
                                              const int* __restrict__ idxv,
                                              float* __restrict__ out) {
  int wave = threadIdx.x >> 6, lane = threadIdx.x & 63;
  int g = blockIdx.x * 4 + wave;               // node 0..16383
  int bN = (g >> 12) << 12;
  float4 q4 = *(const float4*)(qf + (size_t)g * C_ + lane * 4);
  int my = idxv[(size_t)g * 16 + (lane & 15)];
  const float scale = 0.17677669529663687f;    // 1/sqrt(32)

  float s[16];
  float4 vv[16];
#pragma unroll
  for (int j = 0; j < 16; j++) {
    int nb = __shfl(my, j);
    size_t base = (size_t)(bN + nb) * C_ + lane * 4;
    float4 k4 = *(const float4*)(kf + base);
    vv[j] = *(const float4*)(vf + base);
    float p = k4.x * q4.x + k4.y * q4.y + k4.z * q4.z + k4.w * q4.w;
    p += __shfl_xor(p, 1); p += __shfl_xor(p, 2); p += __shfl_xor(p, 4);
    s[j] = p * scale;
  }
  float mx = s[0];
#pragma unroll
  for (int j = 1; j < 16; j++) mx = fmaxf(mx, s[j]);
  float den = 0.f;
#pragma unroll
  for (int j = 0; j < 16; j++) { s[j] = __expf(s[j] - mx); den += s[j]; }
  float inv = 1.0f / den;
  float4 o; o.x = 0.f; o.y = 0.f; o.z = 0.f; o.w = 0.f;
#pragma unroll
  for (int j = 0; j < 16; j++) {
    float w = s[j] * inv;
    o.x = fmaf(w, vv[j].x, o.x); o.y = fmaf(w, vv[j].y, o.y);
    o.z = fmaf(w, vv[j].z, o.z); o.w = fmaf(w, vv[j].w, o.w);
  }
  *(float4*)(out + (size_t)g * C_ + lane * 4) = o;
}

extern "C" void kernel_launch(void* const* d_in, const int* in_sizes, int n_in,
                              void* d_out, int out_size, void* d_ws, size_t ws_size,
                              hipStream_t stream) {
  const float* x  = (const float*)d_in[0];
  const float* Wq = (const float*)d_in[1];
  const float* bq = (const float*)d_in[2];
  const float* Wk = (const float*)d_in[3];
  const float* bk = (const float*)d_in[4];
  const float* Wv = (const float*)d_in[5];
  const float* bv = (const float*)d_in[6];
  float* out = (float*)d_out;

  char* ws = (char*)d_ws;
  float*     sqp  = (float*)(ws + 0);                //  64 KB
  _Float16*  xh   = (_Float16*)(ws + 65536);         //   8 MB
  _Float16*  xl   = (_Float16*)(ws + 8454144);       //   8 MB
  float*     qf   = (float*)(ws + 16842752);         //  16 MB
  float*     kf   = (float*)(ws + 33619968);         //  16 MB
  float*     vf   = (float*)(ws + 50397184);         //  16 MB
  double*    pd   = (double*)(ws + 67174400);        //   8 MB
  int*       idxb = (int*)  (ws + 75563008);         //   1 MB
  _Float16*  whf  = (_Float16*)(ws + 76611584);      // 384 KB
  _Float16*  wlf  = (_Float16*)(ws + 77004800);      // 384 KB (total ~74 MB)

  k_prep  <<<4096, 256, 0, stream>>>(x, sqp, xh, xl);
  k_wsplit<<<768,  256, 0, stream>>>(Wq, Wk, Wv, whf, wlf);
  k_proj  <<<768,  256, 0, stream>>>(xh, xl, whf, wlf, bq, bk, bv, qf, kf, vf);
  k_knn   <<<512,  256, 0, stream>>>(xh, xl, sqp, pd);
  k_kmerge<<<256,  64,  0, stream>>>(pd, idxb);
  k_attn  <<<4096, 256, 0, stream>>>(qf, kf, vf, idxb, out);
}